// Round 8
// baseline (225.268 us; speedup 1.0000x reference)
//
#include <hip/hip_runtime.h>

#define BB 8
#define NN 8192
#define NPOINT 2048
#define NSAMPLE 64
#define CIN 64
#define RADIUS 0.2f
#define R2 (RADIUS * RADIUS)

// d_out layout (flat floats, reference return order)
#define OFF_NEWXYZ 0
#define OFF_FEAT (BB * NPOINT * 3)
#define OFF_INDS (OFF_FEAT + BB * NPOINT * 128)
#define OFF_IDX (OFF_INDS + BB * NPOINT)

typedef _Float16 half8 __attribute__((ext_vector_type(8)));
typedef _Float16 half4 __attribute__((ext_vector_type(4)));
typedef __fp16 f16x2 __attribute__((ext_vector_type(2)));
typedef float floatx16 __attribute__((ext_vector_type(16)));

// Per-wave activation slices, XOR-block-swizzled:
//   addr(row, col) = row*P + ((col>>3) ^ (row & 7))*8 + (col & 7)   [col<64]
// 16B blocks stay intact -> fragment reads remain single ds_read_b128;
// row-strided half4 C-writes become 2-way (free) instead of 4-way.
#define XP 80  // X: K0=80 (64 feat + xyz + bias + zero pad); blocks 8,9 plain
#define HP 64  // H: K=64, all blocks swizzled
#define X_HALVES (64 * XP)                   // 5120
#define H_HALVES (64 * HP)                   // 4096
#define WAVE_HALVES (X_HALVES + H_HALVES)    // 9216 halves = 18432 B/wave
// one-time weight staging (block-shared, overlaps the wave slices):
#define W0_S 0              // pitch 80, 64 rows ->  5120
#define W1_S 5120           // pitch 72, 64 rows ->  9728
#define W2_S 9728           // pitch 64, 128 rows -> 17920 (< 18432)

#define QPW 8  // queries per wave; 1024 blocks = 4 blocks/CU exactly

// ---------------------------------------------------------------------------
// Kernel 1: new_xyz gather + inds passthrough + ball query.
// Wave per query, 4 candidates/lane/iter (k-major keeps first-hit order),
// one-chunk software prefetch to hide global-load latency behind ballots.
// Distance formula must stay qq + nn - 2*dot (reference rounding).
// ---------------------------------------------------------------------------
__global__ __launch_bounds__(256) void ballq_kernel(
    const float* __restrict__ xyz, const int* __restrict__ inds,
    float* __restrict__ out) {
  const int wq = (blockIdx.x * 256 + threadIdx.x) >> 6;  // query id
  const int lane = threadIdx.x & 63;
  const int b = wq >> 11;  // NPOINT = 2048

  const float* xb = xyz + (size_t)b * NN * 3;
  const int ind = inds[wq];
  const float cx = xb[ind * 3 + 0];
  const float cy = xb[ind * 3 + 1];
  const float cz = xb[ind * 3 + 2];

  if (lane == 0) {
    out[OFF_NEWXYZ + (size_t)wq * 3 + 0] = cx;
    out[OFF_NEWXYZ + (size_t)wq * 3 + 1] = cy;
    out[OFF_NEWXYZ + (size_t)wq * 3 + 2] = cz;
    out[OFF_INDS + wq] = (float)ind;
  }

  const float qq = cx * cx + cy * cy + cz * cz;
  float* myidx = out + OFF_IDX + (size_t)wq * NSAMPLE;

  int cnt = 0;
  float ax[4], ay[4], az[4];
#pragma unroll
  for (int k = 0; k < 4; ++k) {
    const float* p = xb + (size_t)(k * 64 + lane) * 3;
    ax[k] = p[0];
    ay[k] = p[1];
    az[k] = p[2];
  }
  for (int j0 = 0; j0 < NN; j0 += 256) {
    float bx[4] = {0}, by[4] = {0}, bz[4] = {0};
    const int jn = j0 + 256;
    if (jn < NN) {  // prefetch next chunk while ballots run on current
#pragma unroll
      for (int k = 0; k < 4; ++k) {
        const float* p = xb + (size_t)(jn + k * 64 + lane) * 3;
        bx[k] = p[0];
        by[k] = p[1];
        bz[k] = p[2];
      }
    }
#pragma unroll
    for (int k = 0; k < 4; ++k) {
      const float nn_ = ax[k] * ax[k] + ay[k] * ay[k] + az[k] * az[k];
      const float dot = cx * ax[k] + cy * ay[k] + cz * az[k];
      const bool hit = (qq + nn_ - 2.0f * dot) < R2;
      const unsigned long long m = __ballot(hit);
      if (hit) {
        const int pos = cnt + (int)__popcll(m & ((1ull << lane) - 1ull));
        if (pos < NSAMPLE) myidx[pos] = (float)(j0 + k * 64 + lane);
      }
      cnt += (int)__popcll(m);
    }
    if (cnt >= NSAMPLE) break;
#pragma unroll
    for (int k = 0; k < 4; ++k) {
      ax[k] = bx[k];
      ay[k] = by[k];
      az[k] = bz[k];
    }
  }
  // Pad: center point always hits itself -> cnt >= 1 -> myidx[0] valid.
  const float f0 = myidx[0];
  if (lane >= cnt) myidx[lane] = f0;
}

// ---------------------------------------------------------------------------
// Kernel 2: barrier-free MFMA MLP. 128-thread block = 2 independent waves,
// each owning one query at a time in a private swizzled LDS slice.
// L0/L1: A = weight fragments (registers), B = activation fragments (b128).
// C/D: lane = sample column, channel rows in groups of 4 -> half4 b64 writes
// (swizzle makes them 2-way/free). L2: A = H1, B = W2' -> lane owns a d2
// column; maxpool = register reduction + 1 shuffle.
// ---------------------------------------------------------------------------
__global__ __launch_bounds__(128, 2) void mlp_mfma(
    const float* __restrict__ xyz, const float* __restrict__ features,
    const int* __restrict__ inds,
    const float* __restrict__ w0, const float* __restrict__ s0,
    const float* __restrict__ t0, const float* __restrict__ w1,
    const float* __restrict__ s1, const float* __restrict__ t1,
    const float* __restrict__ w2, const float* __restrict__ s2,
    const float* __restrict__ t2, float* __restrict__ out) {
  __shared__ _Float16 sm[2 * WAVE_HALVES];  // 36864 B
  __shared__ float t1sm[64];                // +256 B -> 37120 B: 4 blocks/CU
  const int tid = threadIdx.x;
  const int w = tid >> 6;
  const int l = tid & 63;
  const int l31 = l & 31;
  const int h5 = l >> 5;
  const int koff = h5 * 8;  // fragment k-offset in halves

  // ---- stage folded weights (one-time, plain pitches, overlaps slices) ----
  {
    const int d = tid >> 1, hf = tid & 1;
    const float sd0 = s0[d], td0 = t0[d], sd1 = s1[d];
#pragma unroll
    for (int j = 0; j < 40; ++j) {
      const int c = hf * 40 + j;
      float v = 0.0f;
      if (c < 64) v = w0[(3 + c) * 64 + d] * sd0;        // feature channels
      else if (c < 67) v = w0[(c - 64) * 64 + d] * sd0;  // xyz channels
      else if (c == 67) v = td0;                         // bias channel
      sm[W0_S + d * 80 + c] = (_Float16)v;
    }
#pragma unroll
    for (int j = 0; j < 32; ++j) {
      const int c = hf * 32 + j;
      sm[W1_S + d * 72 + c] = (_Float16)(w1[c * 64 + d] * sd1);
    }
    const int ch = tid;  // 0..127
    const float sch = s2[ch];
#pragma unroll
    for (int c = 0; c < 64; ++c)
      sm[W2_S + ch * 64 + c] = (_Float16)(w2[c * 128 + ch] * sch);
    if (tid < 64) t1sm[tid] = t1[tid];
  }
  __syncthreads();

  // ---- hoist weight fragments into registers (block-invariant) ----
  half8 a0f[2][5], a1f[2][4], b2f[4][4];
#pragma unroll
  for (int mt = 0; mt < 2; ++mt)
#pragma unroll
    for (int ks = 0; ks < 5; ++ks)
      a0f[mt][ks] =
          *(const half8*)&sm[W0_S + (mt * 32 + l31) * 80 + ks * 16 + koff];
#pragma unroll
  for (int mt = 0; mt < 2; ++mt)
#pragma unroll
    for (int ks = 0; ks < 4; ++ks)
      a1f[mt][ks] =
          *(const half8*)&sm[W1_S + (mt * 32 + l31) * 72 + ks * 16 + koff];
#pragma unroll
  for (int ct = 0; ct < 4; ++ct)
#pragma unroll
    for (int ks = 0; ks < 4; ++ks)
      b2f[ct][ks] =
          *(const half8*)&sm[W2_S + (ct * 32 + l31) * 64 + ks * 16 + koff];
  float t2v[4];
#pragma unroll
  for (int ct = 0; ct < 4; ++ct) t2v[ct] = t2[ct * 32 + l31];
  __syncthreads();  // fragments hoisted before slices overwrite the region

  _Float16* xbuf = sm + w * WAVE_HALVES;
  _Float16* hbuf = xbuf + X_HALVES;
  const int r7l = l & 7;
  // zero X block 9 (cols 72..79) once; block 8 tail rewritten per query
  {
    half8 z = {};
    *(half8*)&xbuf[l * XP + 72] = z;
  }

  const int wq0 = (blockIdx.x * 2 + w) * QPW;
#pragma unroll 1
  for (int qi = 0; qi < QPW; ++qi) {
    const int q = wq0 + qi;
    const int b = q >> 11;

    // ---- gather + stage X (lane = sample, row l, swizzled blocks) ----
    const int idxs = (int)out[OFF_IDX + (size_t)q * NSAMPLE + l];
    const float* xb = xyz + (size_t)b * NN * 3;
    const int ind = inds[q];
    const float cx = xb[ind * 3 + 0], cy = xb[ind * 3 + 1],
                cz = xb[ind * 3 + 2];
    const float ppx = xb[idxs * 3 + 0], ppy = xb[idxs * 3 + 1],
                ppz = xb[idxs * 3 + 2];
    const float4* fr =
        (const float4*)(features + ((size_t)b * NN + (size_t)idxs) * CIN);
    float4 f[16];
#pragma unroll
    for (int u = 0; u < 16; ++u) f[u] = fr[u];
#pragma unroll
    for (int u = 0; u < 8; ++u) {
      union {
        half8 v;
        f16x2 p[4];
      } hv;
      hv.p[0] = __builtin_amdgcn_cvt_pkrtz(f[2 * u].x, f[2 * u].y);
      hv.p[1] = __builtin_amdgcn_cvt_pkrtz(f[2 * u].z, f[2 * u].w);
      hv.p[2] = __builtin_amdgcn_cvt_pkrtz(f[2 * u + 1].x, f[2 * u + 1].y);
      hv.p[3] = __builtin_amdgcn_cvt_pkrtz(f[2 * u + 1].z, f[2 * u + 1].w);
      *(half8*)&xbuf[l * XP + ((u ^ r7l) << 3)] = hv.v;
    }
    {
      union {
        half8 v;
        f16x2 p[4];
      } xv;
      xv.p[0] =
          __builtin_amdgcn_cvt_pkrtz((ppx - cx) * 5.0f, (ppy - cy) * 5.0f);
      xv.p[1] = __builtin_amdgcn_cvt_pkrtz((ppz - cz) * 5.0f, 1.0f);  // bias
      xv.p[2] = __builtin_amdgcn_cvt_pkrtz(0.0f, 0.0f);
      xv.p[3] = __builtin_amdgcn_cvt_pkrtz(0.0f, 0.0f);
      *(half8*)&xbuf[l * XP + 64] = xv.v;  // block 8, unswizzled
    }

    // ---- L0: C = W0' x X-tiles -> H0[sample][d0] via b64 writes ----
    {
      const int srow = l31;  // per-nt rows srow, srow+32
      half8 xa[2][5];
#pragma unroll
      for (int nt = 0; nt < 2; ++nt) {
        const int r = nt * 32 + srow, r7 = r & 7;
#pragma unroll
        for (int ks = 0; ks < 5; ++ks) {
          const int blk = 2 * ks + h5;
          const int sb = (blk < 8) ? (blk ^ r7) : blk;
          xa[nt][ks] = *(const half8*)&xbuf[r * XP + sb * 8];
        }
      }
#pragma unroll
      for (int mt = 0; mt < 2; ++mt)
#pragma unroll
        for (int nt = 0; nt < 2; ++nt) {
          floatx16 acc;
#pragma unroll
          for (int i = 0; i < 16; ++i) acc[i] = 0.0f;
#pragma unroll
          for (int ks = 0; ks < 5; ++ks)
            acc = __builtin_amdgcn_mfma_f32_32x32x16_f16(a0f[mt][ks],
                                                         xa[nt][ks], acc,
                                                         0, 0, 0);
          const int s = nt * 32 + l31, s7 = s & 7;
#pragma unroll
          for (int g = 0; g < 4; ++g) {
            half4 hv;
#pragma unroll
            for (int r = 0; r < 4; ++r)
              hv[r] = (_Float16)fmaxf(acc[4 * g + r], 0.0f);
            *(half4*)&hbuf[s * HP + (((4 * mt + g) ^ s7) << 3) + 4 * h5] = hv;
          }
        }
    }

    // ---- L1: C = W1' x H0-tiles -> H1[sample][d1] into X cols 0..63 ----
    {
      half8 ha[2][4];
#pragma unroll
      for (int nt = 0; nt < 2; ++nt) {
        const int r = nt * 32 + l31, r7 = r & 7;
#pragma unroll
        for (int ks = 0; ks < 4; ++ks)
          ha[nt][ks] =
              *(const half8*)&hbuf[r * HP + (((2 * ks + h5) ^ r7) << 3)];
      }
#pragma unroll
      for (int mt = 0; mt < 2; ++mt)
#pragma unroll
        for (int nt = 0; nt < 2; ++nt) {
          floatx16 acc;
#pragma unroll
          for (int i = 0; i < 16; ++i) acc[i] = 0.0f;
#pragma unroll
          for (int ks = 0; ks < 4; ++ks)
            acc = __builtin_amdgcn_mfma_f32_32x32x16_f16(a1f[mt][ks],
                                                         ha[nt][ks], acc,
                                                         0, 0, 0);
          const int s = nt * 32 + l31, s7 = s & 7;
#pragma unroll
          for (int g = 0; g < 4; ++g) {
            const float4 tq = *(const float4*)&t1sm[mt * 32 + 8 * g + 4 * h5];
            half4 hv;
            hv[0] = (_Float16)fmaxf(acc[4 * g + 0] + tq.x, 0.0f);
            hv[1] = (_Float16)fmaxf(acc[4 * g + 1] + tq.y, 0.0f);
            hv[2] = (_Float16)fmaxf(acc[4 * g + 2] + tq.z, 0.0f);
            hv[3] = (_Float16)fmaxf(acc[4 * g + 3] + tq.w, 0.0f);
            *(half4*)&xbuf[s * XP + (((4 * mt + g) ^ s7) << 3) + 4 * h5] = hv;
          }
        }
    }

    // ---- L2: Y = H1 @ W2' (lane owns d2 column), fused maxpool ----
    {
      half8 h1a[2][4];
#pragma unroll
      for (int st = 0; st < 2; ++st) {
        const int r = st * 32 + l31, r7 = r & 7;
#pragma unroll
        for (int ks = 0; ks < 4; ++ks)
          h1a[st][ks] =
              *(const half8*)&xbuf[r * XP + (((2 * ks + h5) ^ r7) << 3)];
      }
#pragma unroll
      for (int ct = 0; ct < 4; ++ct) {
        floatx16 aA, aB;
#pragma unroll
        for (int i = 0; i < 16; ++i) {
          aA[i] = 0.0f;
          aB[i] = 0.0f;
        }
#pragma unroll
        for (int ks = 0; ks < 4; ++ks) {
          aA = __builtin_amdgcn_mfma_f32_32x32x16_f16(h1a[0][ks], b2f[ct][ks],
                                                      aA, 0, 0, 0);
          aB = __builtin_amdgcn_mfma_f32_32x32x16_f16(h1a[1][ks], b2f[ct][ks],
                                                      aB, 0, 0, 0);
        }
        float m = fmaxf(aA[0], aB[0]);
#pragma unroll
        for (int i = 1; i < 16; ++i) m = fmaxf(m, fmaxf(aA[i], aB[i]));
        float v = fmaxf(m + t2v[ct], 0.0f);  // relu(max+t) == max(relu(+t))
        v = fmaxf(v, __shfl_xor(v, 32, 64));  // merge complementary row halves
        if (l < 32) out[OFF_FEAT + (size_t)q * 128 + ct * 32 + l] = v;
      }
    }
  }
}

extern "C" void kernel_launch(void* const* d_in, const int* in_sizes, int n_in,
                              void* d_out, int out_size, void* d_ws,
                              size_t ws_size, hipStream_t stream) {
  const float* xyz = (const float*)d_in[0];
  const float* features = (const float*)d_in[1];
  const int* inds = (const int*)d_in[2];
  const float* w0 = (const float*)d_in[3];
  const float* s0 = (const float*)d_in[4];
  const float* t0 = (const float*)d_in[5];
  const float* w1 = (const float*)d_in[6];
  const float* s1 = (const float*)d_in[7];
  const float* t1 = (const float*)d_in[8];
  const float* w2 = (const float*)d_in[9];
  const float* s2 = (const float*)d_in[10];
  const float* t2 = (const float*)d_in[11];
  float* out = (float*)d_out;

  const int nquery = BB * NPOINT;  // 16384
  ballq_kernel<<<nquery / 4, 256, 0, stream>>>(xyz, inds, out);
  // 2 waves/block * QPW queries each -> 1024 blocks = 4 blocks/CU
  mlp_mfma<<<nquery / (2 * QPW), 128, 0, stream>>>(
      xyz, features, inds, w0, s0, t0, w1, s1, t1, w2, s2, t2, out);
}